// Round 7
// baseline (517.707 us; speedup 1.0000x reference)
//
#include <hip/hip_runtime.h>

#define NN 50000
#define NE 200000
#define NG 512
#define NB 6250      // node blocks (8 nodes each)
#define FN 64
#define FE 16
#define FE2 32
#define H 32
#define NL 3
#define EPSV 1e-5f

// ================= mega prep: Wt repack | edge emb | degB/cnt | node emb+lin0 =================
// Wt2[l][i][c], c=kf*32+o (row i = 4 KB contiguous). agg zeroed by emb_lin part.
__global__ void k_prep(const float* __restrict__ Wnn, float* __restrict__ Wt2,
                       const float* __restrict__ eattr, const float* __restrict__ We,
                       const float* __restrict__ be, float* __restrict__ ea,
                       const int* __restrict__ src, const int* __restrict__ batch,
                       int* __restrict__ degB, float* __restrict__ cnt,
                       const float* __restrict__ x, const float* __restrict__ Wn,
                       const float* __restrict__ bno, const float* __restrict__ Wr,
                       const float* __restrict__ bc, const float* __restrict__ bnn,
                       float* __restrict__ h, float* __restrict__ z,
                       float* __restrict__ u, float* __restrict__ agg) {
    __shared__ __align__(16) float smem[4928];
    int t = threadIdx.x;
    int b = blockIdx.x;
    if (b < 384) {                       // ---- Wt repack (98304 elems)
        int idx = b * 256 + t;
        int c = idx & 1023, i = (idx >> 10) & 31, l = idx >> 15;
        int kf = c >> 5, o = c & 31;
        Wt2[idx] = Wnn[((size_t)(l * 32 + kf)) * 1024 + i * 32 + o];
    } else if (b < 25384) {              // ---- edge embedding (8 edges/block)
        float* sW = smem;
        for (int j = t; j < FE * FE2; j += 256) sW[j] = We[j];
        __syncthreads();
        int e = (b - 384) * 8 + (t >> 5);
        int o = t & 31;
        const float* er = eattr + (size_t)e * FE;
        float acc = be[o];
#pragma unroll
        for (int i = 0; i < FE; i++) acc += er[i] * sW[i * FE2 + o];
        ea[(size_t)e * FE2 + o] = acc;
    } else if (b < 26166) {              // ---- bucket degrees + graph counts
        int e = (b - 25384) * 256 + t;
        if (e < NE) atomicAdd(&degB[src[e] >> 3], 1);
        if (e < NN) atomicAdd(&cnt[batch[e]], 1.f);
    } else {                             // ---- node emb + layer0 node-linear (+agg zero)
        float* sW  = smem;               // 2048
        float* sWr = smem + 2048;        // 1024
        float* sBn = smem + 3072;        // 1024
        float* sx  = smem + 4096;        // 512
        float* sh  = smem + 4608;        // 256
        for (int j = t; j < FN * H; j += 256) sW[j] = Wn[j];
        for (int j = t; j < H * H; j += 256) { sWr[j] = Wr[j]; sBn[j] = bnn[j]; }
        int nb = (b - 26166) * 8;
        if (t < 128) {
            int n = t >> 4, qq = t & 15;
            *(float4*)&sx[n * FN + qq * 4] =
                *(const float4*)(x + (size_t)(nb + n) * FN + qq * 4);
        }
        __syncthreads();
        int node = t >> 5, o = t & 31;
        float acc = bno[o];
#pragma unroll 16
        for (int i = 0; i < FN; i++) acc += sx[node * FN + i] * sW[i * H + o];
        sh[node * H + o] = acc;
        size_t idx = (size_t)(nb + node) * H + o;
        h[idx] = acc;
        __syncthreads();
        float a = bc[o], bacc = 0.f;
#pragma unroll
        for (int i = 0; i < H; i++) {
            float hv = sh[node * H + i];
            a += hv * sWr[i * H + o];
            bacc += hv * sBn[i * H + o];
        }
        z[idx] = a;
        u[idx] = bacc;
        agg[idx] = 0.f;
    }
}

// ================= bucket scan (single block): rowptrB/cursorB =================
__global__ void k_scanB(const int* __restrict__ degB, int* __restrict__ rowptrB,
                        int* __restrict__ cursorB) {
    __shared__ int ssum[1024];
    int t = threadIdx.x;
    int loc[7];
    int base = t * 7;
    int s = 0;
#pragma unroll
    for (int i = 0; i < 7; i++) {
        int idx = base + i;
        loc[i] = (idx < NB) ? degB[idx] : 0;
        s += loc[i];
    }
    ssum[t] = s;
    for (int off = 1; off < 1024; off <<= 1) {
        __syncthreads();
        int tv = (t >= off) ? ssum[t - off] : 0;
        __syncthreads();
        ssum[t] += tv;
    }
    __syncthreads();
    int run = ssum[t] - s;
#pragma unroll
    for (int i = 0; i < 7; i++) {
        int idx = base + i;
        if (idx < NB) { rowptrB[idx] = run; cursorB[idx] = run; run += loc[i]; }
    }
    if (t == 1023) rowptrB[NB] = ssum[1023];
}

__global__ void k_fill(const int* __restrict__ src, int* __restrict__ cursorB,
                       int* __restrict__ eid) {
    int e = blockIdx.x * 256 + threadIdx.x;
    if (e >= NE) return;
    int p = atomicAdd(&cursorB[src[e] >> 3], 1);
    eid[p] = e;
}

// ================= fused NNConv v4 =================
// Phase A (barrier-free): wave w owns 256-col group, streams Wt rows from L2 as
// coalesced float4, T[8][1024] -> LDS. Phase B (vectorized): batches of 32 edges;
// 8 lanes/edge, 4 outputs/lane; T via ds_read_b128, ea via broadcast float4 from
// padded sea; 4 scalar atomics/lane into agg[dst]. Block 0 zeroes stats.
__global__ __launch_bounds__(256, 4) void k_conv(
    const float* __restrict__ h, const float* __restrict__ u,
    const float* __restrict__ ea, const float* __restrict__ Wt2l,
    const int* __restrict__ rowptrB, const int* __restrict__ eid,
    const int* __restrict__ src, const int* __restrict__ dst,
    float* __restrict__ agg, float* __restrict__ stats) {
    __shared__ __align__(16) float st[8][1024];   // 32 KB T tile
    __shared__ __align__(16) float shh[8][32];
    __shared__ __align__(16) float su[8][32];
    __shared__ __align__(16) float sea[32][36];   // padded: bank-spread + 16B aligned
    __shared__ int ssn[32];
    __shared__ int sdd[32];
    int t = threadIdx.x;
    int nb0 = blockIdx.x * 8;
    if (blockIdx.x == 0 && t < 64) stats[t] = 0.f;

    if (t < 64) {
        int n = t >> 3, qq = t & 7;
        *(float4*)&shh[n][qq * 4] = *(const float4*)(h + (size_t)(nb0 + n) * H + qq * 4);
        *(float4*)&su[n][qq * 4] = *(const float4*)(u + (size_t)(nb0 + n) * H + qq * 4);
    }
    __syncthreads();

    // ---- Phase A
    {
        int q = t & 63, cg = t >> 6;
        float4 acc[8];
#pragma unroll
        for (int n = 0; n < 8; n++) acc[n] = make_float4(0.f, 0.f, 0.f, 0.f);
        const float4* wp = (const float4*)Wt2l + cg * 64 + q;
#pragma unroll
        for (int i4 = 0; i4 < 8; i4++) {
            float4 w0 = wp[(i4 * 4 + 0) * 256];
            float4 w1 = wp[(i4 * 4 + 1) * 256];
            float4 w2 = wp[(i4 * 4 + 2) * 256];
            float4 w3 = wp[(i4 * 4 + 3) * 256];
#pragma unroll
            for (int n = 0; n < 8; n++) {
                float4 hv = *(const float4*)&shh[n][i4 * 4];
                acc[n].x += hv.x * w0.x; acc[n].y += hv.x * w0.y;
                acc[n].z += hv.x * w0.z; acc[n].w += hv.x * w0.w;
                acc[n].x += hv.y * w1.x; acc[n].y += hv.y * w1.y;
                acc[n].z += hv.y * w1.z; acc[n].w += hv.y * w1.w;
                acc[n].x += hv.z * w2.x; acc[n].y += hv.z * w2.y;
                acc[n].z += hv.z * w2.z; acc[n].w += hv.z * w2.w;
                acc[n].x += hv.w * w3.x; acc[n].y += hv.w * w3.y;
                acc[n].z += hv.w * w3.z; acc[n].w += hv.w * w3.w;
            }
        }
#pragma unroll
        for (int n = 0; n < 8; n++)
            *(float4*)&st[n][cg * 256 + q * 4] = acc[n];
    }
    __syncthreads();   // T tile complete

    // ---- Phase B
    int E0 = rowptrB[blockIdx.x], E1 = rowptrB[blockIdx.x + 1];
    int eslot = t >> 3, r = t & 7;
    for (int j0 = E0; j0 < E1; j0 += 32) {
        int bn = E1 - j0; if (bn > 32) bn = 32;
        if (j0 > E0) __syncthreads();     // protect sea reuse
        if (eslot < bn) {
            int e = eid[j0 + eslot];
            *(float4*)&sea[eslot][r * 4] =
                *(const float4*)(ea + (size_t)e * FE2 + r * 4);
            if (r == 0) { ssn[eslot] = src[e] - nb0; sdd[eslot] = dst[e]; }
        }
        __syncthreads();
        if (eslot < bn) {
            int ln = ssn[eslot], d = sdd[eslot];
            float4 m = *(const float4*)&su[ln][r * 4];
            const float* tp = &st[ln][r * 4];
#pragma unroll
            for (int k4 = 0; k4 < 8; k4++) {
                float4 se = *(const float4*)&sea[eslot][k4 * 4];
                float4 w0 = *(const float4*)&tp[(k4 * 4 + 0) * 32];
                float4 w1 = *(const float4*)&tp[(k4 * 4 + 1) * 32];
                float4 w2 = *(const float4*)&tp[(k4 * 4 + 2) * 32];
                float4 w3 = *(const float4*)&tp[(k4 * 4 + 3) * 32];
                m.x += se.x * w0.x + se.y * w1.x + se.z * w2.x + se.w * w3.x;
                m.y += se.x * w0.y + se.y * w1.y + se.z * w2.y + se.w * w3.y;
                m.z += se.x * w0.z + se.y * w1.z + se.z * w2.z + se.w * w3.z;
                m.w += se.x * w0.w + se.y * w1.w + se.z * w2.w + se.w * w3.w;
            }
            float* ap = agg + (size_t)d * H + r * 4;
            atomicAdd(ap + 0, m.x);
            atomicAdd(ap + 1, m.y);
            atomicAdd(ap + 2, m.z);
            atomicAdd(ap + 3, m.w);
        }
    }
}

// ================= z += agg (agg re-zeroed); per-channel sum & sumsq =================
__global__ void k_add_stats(float* __restrict__ z, float* __restrict__ agg,
                            float* __restrict__ stats) {
    __shared__ float red[256];
    int t = threadIdx.x;
    float s = 0.f, s2 = 0.f;
    for (size_t idx = (size_t)blockIdx.x * 256 + t; idx < (size_t)NN * H;
         idx += (size_t)gridDim.x * 256) {
        float v = z[idx] + agg[idx];
        z[idx] = v;
        agg[idx] = 0.f;
        s += v;
        s2 += v * v;
    }
    red[t] = s;
    __syncthreads();
    for (int st = 128; st >= 32; st >>= 1) {
        if (t < st) red[t] += red[t + st];
        __syncthreads();
    }
    if (t < 32) atomicAdd(&stats[t], red[t]);
    __syncthreads();
    red[t] = s2;
    __syncthreads();
    for (int st = 128; st >= 32; st >>= 1) {
        if (t < st) red[t] += red[t + st];
        __syncthreads();
    }
    if (t < 32) atomicAdd(&stats[32 + t], red[t]);
}

// ================= fused BN+ReLU -> next layer's node linear =================
__global__ void k_bn_lin(const float* __restrict__ z, const float* __restrict__ stats,
                         const float* __restrict__ gm, const float* __restrict__ bt,
                         const float* __restrict__ Wr, const float* __restrict__ bc,
                         const float* __restrict__ bnn, float* __restrict__ hout,
                         float* __restrict__ zout, float* __restrict__ uout) {
    __shared__ float sWr[H * H];
    __shared__ float sBn[H * H];
    __shared__ float sh[8][32];
    int t = threadIdx.x;
    for (int j = t; j < H * H; j += 256) { sWr[j] = Wr[j]; sBn[j] = bnn[j]; }
    int node = t >> 5, o = t & 31;
    size_t idx = (size_t)(blockIdx.x * 8 + node) * H + o;
    const float invn = 1.0f / (float)NN;
    float mu = stats[o] * invn;
    float var = stats[32 + o] * invn - mu * mu;
    float v = (z[idx] - mu) * rsqrtf(var + EPSV) * gm[o] + bt[o];
    v = v > 0.f ? v : 0.f;
    sh[node][o] = v;
    hout[idx] = v;
    __syncthreads();
    float a = bc[o], bacc = 0.f;
#pragma unroll
    for (int i = 0; i < H; i++) {
        float hv = sh[node][i];
        a += hv * sWr[i * H + o];
        bacc += hv * sBn[i * H + o];
    }
    zout[idx] = a;
    uout[idx] = bacc;
}

// ================= fused BN+ReLU -> graph pool (last layer) =================
__global__ void k_bn_pool(const float* __restrict__ z, const float* __restrict__ stats,
                          const float* __restrict__ gm, const float* __restrict__ bt,
                          const int* __restrict__ batch, float* __restrict__ gsum) {
    int idx = blockIdx.x * 256 + threadIdx.x;
    if (idx >= NN * H) return;
    int n = idx >> 5, o = idx & 31;
    const float invn = 1.0f / (float)NN;
    float mu = stats[o] * invn;
    float var = stats[32 + o] * invn - mu * mu;
    float v = (z[idx] - mu) * rsqrtf(var + EPSV) * gm[o] + bt[o];
    v = v > 0.f ? v : 0.f;
    atomicAdd(&gsum[(size_t)batch[n] * H + o], v);
}

// ================= head =================
__global__ void k_head(const float* __restrict__ gsum, const float* __restrict__ cnt,
                       const float* __restrict__ W2, const float* __restrict__ b2,
                       const float* __restrict__ W3, const float* __restrict__ b3,
                       float* __restrict__ out) {
    __shared__ float sW2[H * 16];
    __shared__ float sW3[16];
    __shared__ float sb2[16];
    int t = threadIdx.x;
    for (int j = t; j < H * 16; j += 256) sW2[j] = W2[j];
    if (t < 16) { sW3[t] = W3[t]; sb2[t] = b2[t]; }
    __syncthreads();
    int g = blockIdx.x * 256 + t;
    if (g >= NG) return;
    float inv = 1.0f / fmaxf(cnt[g], 1.0f);
    float gx[H];
#pragma unroll
    for (int i = 0; i < H; i++) gx[i] = gsum[g * H + i] * inv;
    float o3 = b3[0];
#pragma unroll
    for (int j = 0; j < 16; j++) {
        float hh = sb2[j];
#pragma unroll
        for (int i = 0; i < H; i++) hh += gx[i] * sW2[i * 16 + j];
        hh = hh > 0.f ? hh : 0.f;
        o3 += hh * sW3[j];
    }
    out[g] = o3;
}

extern "C" void kernel_launch(void* const* d_in, const int* in_sizes, int n_in,
                              void* d_out, int out_size, void* d_ws, size_t ws_size,
                              hipStream_t stream) {
    const float* x      = (const float*)d_in[0];
    const float* eattr  = (const float*)d_in[1];
    const float* W_node = (const float*)d_in[2];
    const float* b_node = (const float*)d_in[3];
    const float* W_edge = (const float*)d_in[4];
    const float* b_edge = (const float*)d_in[5];
    const float* W_nn   = (const float*)d_in[6];
    const float* b_nn   = (const float*)d_in[7];
    const float* W_root = (const float*)d_in[8];
    const float* b_conv = (const float*)d_in[9];
    const float* gamma  = (const float*)d_in[10];
    const float* beta   = (const float*)d_in[11];
    const float* W2     = (const float*)d_in[12];
    const float* b2     = (const float*)d_in[13];
    const float* W3     = (const float*)d_in[14];
    const float* b3     = (const float*)d_in[15];
    const int* eidx     = (const int*)d_in[16];
    const int* batch    = (const int*)d_in[17];
    const int* src = eidx;
    const int* dst = eidx + NE;
    float* out = (float*)d_out;

    const size_t NNH = (size_t)NN * H;
    float* ws = (float*)d_ws;
    float* h      = ws;
    float* z      = h + NNH;
    float* u      = z + NNH;
    float* agg    = u + NNH;
    float* stats  = agg + NNH;                 // 64
    float* ea     = stats + 64;                // NE*32
    float* Wt     = ea + (size_t)NE * FE2;     // 3*32768
    int*   degB   = (int*)(Wt + (size_t)NL * 32768);   // NB
    float* gsum   = (float*)(degB + NB);       // NG*32 (contiguous with degB,cnt: one memset)
    float* cnt    = gsum + (size_t)NG * H;     // NG
    int*   rowptrB = (int*)(cnt + NG);         // NB+1
    int*   cursorB = rowptrB + NB + 1;         // NB
    int*   eid    = cursorB + NB;              // NE

    // zero degB | gsum | cnt in one shot
    hipMemsetAsync(degB, 0, (NB + NG * H + NG) * sizeof(int), stream);

    // mega prep: Wt repack (384) | edge emb (25000) | degB/cnt (782) | emb+lin0 (6250)
    k_prep<<<384 + 25000 + 782 + 6250, 256, 0, stream>>>(
        W_nn, Wt, eattr, W_edge, b_edge, ea, src, batch, degB, cnt,
        x, W_node, b_node, W_root, b_conv, b_nn, h, z, u, agg);
    k_scanB<<<1, 1024, 0, stream>>>(degB, rowptrB, cursorB);
    k_fill<<<(NE + 255) / 256, 256, 0, stream>>>(src, cursorB, eid);

    for (int l = 0; l < NL; l++) {
        k_conv<<<NB, 256, 0, stream>>>(h, u, ea, Wt + (size_t)l * 32768,
                                       rowptrB, eid, src, dst, agg, stats);
        k_add_stats<<<512, 256, 0, stream>>>(z, agg, stats);
        if (l < NL - 1) {
            k_bn_lin<<<NB, 256, 0, stream>>>(z, stats, gamma + l * H, beta + l * H,
                                             W_root + (l + 1) * H * H,
                                             b_conv + (l + 1) * H,
                                             b_nn + (size_t)(l + 1) * H * H,
                                             h, z, u);
        } else {
            k_bn_pool<<<NB, 256, 0, stream>>>(z, stats, gamma + l * H, beta + l * H,
                                              batch, gsum);
        }
    }

    k_head<<<2, 256, 0, stream>>>(gsum, cnt, W2, b2, W3, b3, out);
}

// Round 8
// 450.022 us; speedup vs baseline: 1.1504x; 1.1504x over previous
//
#include <hip/hip_runtime.h>

#define NN 50000
#define NE 200000
#define NG 512
#define NB 6250      // node blocks (8 nodes each)
#define FN 64
#define FE 16
#define FE2 32
#define H 32
#define NL 3
#define EPSV 1e-5f

// ================= mega prep: Wt repack | edge emb | degB/cnt | node emb+lin0 =================
// Wt2[l][i][c], c=kf*32+o (row i = 4 KB contiguous). agg zeroed by emb_lin part.
__global__ void k_prep(const float* __restrict__ Wnn, float* __restrict__ Wt2,
                       const float* __restrict__ eattr, const float* __restrict__ We,
                       const float* __restrict__ be, float* __restrict__ ea,
                       const int* __restrict__ src, const int* __restrict__ batch,
                       int* __restrict__ degB, float* __restrict__ cnt,
                       const float* __restrict__ x, const float* __restrict__ Wn,
                       const float* __restrict__ bno, const float* __restrict__ Wr,
                       const float* __restrict__ bc, const float* __restrict__ bnn,
                       float* __restrict__ h, float* __restrict__ z,
                       float* __restrict__ u, float* __restrict__ agg) {
    __shared__ __align__(16) float smem[4928];
    int t = threadIdx.x;
    int b = blockIdx.x;
    if (b < 384) {                       // ---- Wt repack (98304 elems)
        int idx = b * 256 + t;
        int c = idx & 1023, i = (idx >> 10) & 31, l = idx >> 15;
        int kf = c >> 5, o = c & 31;
        Wt2[idx] = Wnn[((size_t)(l * 32 + kf)) * 1024 + i * 32 + o];
    } else if (b < 25384) {              // ---- edge embedding (8 edges/block)
        float* sW = smem;
        for (int j = t; j < FE * FE2; j += 256) sW[j] = We[j];
        __syncthreads();
        int e = (b - 384) * 8 + (t >> 5);
        int o = t & 31;
        const float* er = eattr + (size_t)e * FE;
        float acc = be[o];
#pragma unroll
        for (int i = 0; i < FE; i++) acc += er[i] * sW[i * FE2 + o];
        ea[(size_t)e * FE2 + o] = acc;
    } else if (b < 26166) {              // ---- bucket degrees + graph counts
        int e = (b - 25384) * 256 + t;
        if (e < NE) atomicAdd(&degB[src[e] >> 3], 1);
        if (e < NN) atomicAdd(&cnt[batch[e]], 1.f);
    } else {                             // ---- node emb + layer0 node-linear (+agg zero)
        float* sW  = smem;               // 2048
        float* sWr = smem + 2048;        // 1024
        float* sBn = smem + 3072;        // 1024
        float* sx  = smem + 4096;        // 512
        float* sh  = smem + 4608;        // 256
        for (int j = t; j < FN * H; j += 256) sW[j] = Wn[j];
        for (int j = t; j < H * H; j += 256) { sWr[j] = Wr[j]; sBn[j] = bnn[j]; }
        int nb = (b - 26166) * 8;
        if (t < 128) {
            int n = t >> 4, qq = t & 15;
            *(float4*)&sx[n * FN + qq * 4] =
                *(const float4*)(x + (size_t)(nb + n) * FN + qq * 4);
        }
        __syncthreads();
        int node = t >> 5, o = t & 31;
        float acc = bno[o];
#pragma unroll 16
        for (int i = 0; i < FN; i++) acc += sx[node * FN + i] * sW[i * H + o];
        sh[node * H + o] = acc;
        size_t idx = (size_t)(nb + node) * H + o;
        h[idx] = acc;
        __syncthreads();
        float a = bc[o], bacc = 0.f;
#pragma unroll
        for (int i = 0; i < H; i++) {
            float hv = sh[node * H + i];
            a += hv * sWr[i * H + o];
            bacc += hv * sBn[i * H + o];
        }
        z[idx] = a;
        u[idx] = bacc;
        agg[idx] = 0.f;
    }
}

// ================= bucket scan (single block): rowptrB/cursorB =================
__global__ void k_scanB(const int* __restrict__ degB, int* __restrict__ rowptrB,
                        int* __restrict__ cursorB) {
    __shared__ int ssum[1024];
    int t = threadIdx.x;
    int loc[7];
    int base = t * 7;
    int s = 0;
#pragma unroll
    for (int i = 0; i < 7; i++) {
        int idx = base + i;
        loc[i] = (idx < NB) ? degB[idx] : 0;
        s += loc[i];
    }
    ssum[t] = s;
    for (int off = 1; off < 1024; off <<= 1) {
        __syncthreads();
        int tv = (t >= off) ? ssum[t - off] : 0;
        __syncthreads();
        ssum[t] += tv;
    }
    __syncthreads();
    int run = ssum[t] - s;
#pragma unroll
    for (int i = 0; i < 7; i++) {
        int idx = base + i;
        if (idx < NB) { rowptrB[idx] = run; cursorB[idx] = run; run += loc[i]; }
    }
    if (t == 1023) rowptrB[NB] = ssum[1023];
}

__global__ void k_fill(const int* __restrict__ src, int* __restrict__ cursorB,
                       int* __restrict__ eid) {
    int e = blockIdx.x * 256 + threadIdx.x;
    if (e >= NE) return;
    int p = atomicAdd(&cursorB[src[e] >> 3], 1);
    eid[p] = e;
}

// ================= fused NNConv v5 =================
// Phase A (barrier-free): wave w owns 256-col group, streams Wt rows from L2 as
// coalesced float4, T[8][1024] -> LDS.
// Phase B (wave-independent, NO block barriers): each wave owns 2 edges/iter.
// Lanes stage ea rows into the wave's private double-buffered sea slot (same-wave
// LDS is in-order), then 8x broadcast float4 sea reads + 32 conflict-free b32 T
// reads (bank=o, 2 lanes/bank = free) per edge; one atomicAdd per lane.
__global__ __launch_bounds__(256, 4) void k_conv(
    const float* __restrict__ h, const float* __restrict__ u,
    const float* __restrict__ ea, const float* __restrict__ Wt2l,
    const int* __restrict__ rowptrB, const int* __restrict__ eid,
    const int* __restrict__ src, const int* __restrict__ dst,
    float* __restrict__ agg, float* __restrict__ stats) {
    __shared__ __align__(16) float st[8][1024];   // 32 KB T tile
    __shared__ __align__(16) float shh[8][32];
    __shared__ __align__(16) float su[8][32];
    __shared__ __align__(16) float sea[4][2][64]; // per-wave double-buffered ea
    int t = threadIdx.x;
    int nb0 = blockIdx.x * 8;
    if (blockIdx.x == 0 && t < 64) stats[t] = 0.f;

    if (t < 64) {
        int n = t >> 3, qq = t & 7;
        *(float4*)&shh[n][qq * 4] = *(const float4*)(h + (size_t)(nb0 + n) * H + qq * 4);
        *(float4*)&su[n][qq * 4] = *(const float4*)(u + (size_t)(nb0 + n) * H + qq * 4);
    }
    __syncthreads();

    // ---- Phase A
    {
        int q = t & 63, cg = t >> 6;
        float4 acc[8];
#pragma unroll
        for (int n = 0; n < 8; n++) acc[n] = make_float4(0.f, 0.f, 0.f, 0.f);
        const float4* wp = (const float4*)Wt2l + cg * 64 + q;
#pragma unroll
        for (int i4 = 0; i4 < 8; i4++) {
            float4 w0 = wp[(i4 * 4 + 0) * 256];
            float4 w1 = wp[(i4 * 4 + 1) * 256];
            float4 w2 = wp[(i4 * 4 + 2) * 256];
            float4 w3 = wp[(i4 * 4 + 3) * 256];
#pragma unroll
            for (int n = 0; n < 8; n++) {
                float4 hv = *(const float4*)&shh[n][i4 * 4];
                acc[n].x += hv.x * w0.x; acc[n].y += hv.x * w0.y;
                acc[n].z += hv.x * w0.z; acc[n].w += hv.x * w0.w;
                acc[n].x += hv.y * w1.x; acc[n].y += hv.y * w1.y;
                acc[n].z += hv.y * w1.z; acc[n].w += hv.y * w1.w;
                acc[n].x += hv.z * w2.x; acc[n].y += hv.z * w2.y;
                acc[n].z += hv.z * w2.z; acc[n].w += hv.z * w2.w;
                acc[n].x += hv.w * w3.x; acc[n].y += hv.w * w3.y;
                acc[n].z += hv.w * w3.z; acc[n].w += hv.w * w3.w;
            }
        }
#pragma unroll
        for (int n = 0; n < 8; n++)
            *(float4*)&st[n][cg * 256 + q * 4] = acc[n];
    }
    __syncthreads();   // T tile complete

    // ---- Phase B (no block barriers)
    int E0 = rowptrB[blockIdx.x], E1 = rowptrB[blockIdx.x + 1];
    int w = t >> 6;
    int lane = t & 63;
    int hw = lane >> 5;
    int o = lane & 31;
    int buf = 0;
    for (int jb = E0 + 2 * w; jb < E1; jb += 8, buf ^= 1) {
        int j = jb + hw;
        bool act = (j < E1);
        int e = 0, sn = 0, d = 0;
        float eav = 0.f;
        if (act) {
            e = eid[j];
            sn = src[e] - nb0;
            d = dst[e];
            eav = ea[(size_t)e * FE2 + o];
            sea[w][buf][hw * 32 + o] = eav;
        }
        __builtin_amdgcn_wave_barrier();   // keep LDS write before reads (same wave)
        if (act) {
            const float* seaw = &sea[w][buf][hw * 32];
            float m = su[sn][o];
            const float* tp = &st[sn][0];
#pragma unroll
            for (int k4 = 0; k4 < 8; k4++) {
                float4 se = *(const float4*)&seaw[k4 * 4];
                m += se.x * tp[(k4 * 4 + 0) * 32 + o];
                m += se.y * tp[(k4 * 4 + 1) * 32 + o];
                m += se.z * tp[(k4 * 4 + 2) * 32 + o];
                m += se.w * tp[(k4 * 4 + 3) * 32 + o];
            }
            atomicAdd(&agg[(size_t)d * H + o], m);
        }
        __builtin_amdgcn_wave_barrier();
    }
}

// ================= z += agg (agg re-zeroed); per-channel sum & sumsq =================
__global__ void k_add_stats(float* __restrict__ z, float* __restrict__ agg,
                            float* __restrict__ stats) {
    __shared__ float red[256];
    int t = threadIdx.x;
    float s = 0.f, s2 = 0.f;
    for (size_t idx = (size_t)blockIdx.x * 256 + t; idx < (size_t)NN * H;
         idx += (size_t)gridDim.x * 256) {
        float v = z[idx] + agg[idx];
        z[idx] = v;
        agg[idx] = 0.f;
        s += v;
        s2 += v * v;
    }
    red[t] = s;
    __syncthreads();
    for (int st = 128; st >= 32; st >>= 1) {
        if (t < st) red[t] += red[t + st];
        __syncthreads();
    }
    if (t < 32) atomicAdd(&stats[t], red[t]);
    __syncthreads();
    red[t] = s2;
    __syncthreads();
    for (int st = 128; st >= 32; st >>= 1) {
        if (t < st) red[t] += red[t + st];
        __syncthreads();
    }
    if (t < 32) atomicAdd(&stats[32 + t], red[t]);
}

// ================= fused BN+ReLU -> next layer's node linear =================
__global__ void k_bn_lin(const float* __restrict__ z, const float* __restrict__ stats,
                         const float* __restrict__ gm, const float* __restrict__ bt,
                         const float* __restrict__ Wr, const float* __restrict__ bc,
                         const float* __restrict__ bnn, float* __restrict__ hout,
                         float* __restrict__ zout, float* __restrict__ uout) {
    __shared__ float sWr[H * H];
    __shared__ float sBn[H * H];
    __shared__ float sh[8][32];
    int t = threadIdx.x;
    for (int j = t; j < H * H; j += 256) { sWr[j] = Wr[j]; sBn[j] = bnn[j]; }
    int node = t >> 5, o = t & 31;
    size_t idx = (size_t)(blockIdx.x * 8 + node) * H + o;
    const float invn = 1.0f / (float)NN;
    float mu = stats[o] * invn;
    float var = stats[32 + o] * invn - mu * mu;
    float v = (z[idx] - mu) * rsqrtf(var + EPSV) * gm[o] + bt[o];
    v = v > 0.f ? v : 0.f;
    sh[node][o] = v;
    hout[idx] = v;
    __syncthreads();
    float a = bc[o], bacc = 0.f;
#pragma unroll
    for (int i = 0; i < H; i++) {
        float hv = sh[node][i];
        a += hv * sWr[i * H + o];
        bacc += hv * sBn[i * H + o];
    }
    zout[idx] = a;
    uout[idx] = bacc;
}

// ================= fused BN+ReLU -> graph pool (last layer) =================
__global__ void k_bn_pool(const float* __restrict__ z, const float* __restrict__ stats,
                          const float* __restrict__ gm, const float* __restrict__ bt,
                          const int* __restrict__ batch, float* __restrict__ gsum) {
    int idx = blockIdx.x * 256 + threadIdx.x;
    if (idx >= NN * H) return;
    int n = idx >> 5, o = idx & 31;
    const float invn = 1.0f / (float)NN;
    float mu = stats[o] * invn;
    float var = stats[32 + o] * invn - mu * mu;
    float v = (z[idx] - mu) * rsqrtf(var + EPSV) * gm[o] + bt[o];
    v = v > 0.f ? v : 0.f;
    atomicAdd(&gsum[(size_t)batch[n] * H + o], v);
}

// ================= head =================
__global__ void k_head(const float* __restrict__ gsum, const float* __restrict__ cnt,
                       const float* __restrict__ W2, const float* __restrict__ b2,
                       const float* __restrict__ W3, const float* __restrict__ b3,
                       float* __restrict__ out) {
    __shared__ float sW2[H * 16];
    __shared__ float sW3[16];
    __shared__ float sb2[16];
    int t = threadIdx.x;
    for (int j = t; j < H * 16; j += 256) sW2[j] = W2[j];
    if (t < 16) { sW3[t] = W3[t]; sb2[t] = b2[t]; }
    __syncthreads();
    int g = blockIdx.x * 256 + t;
    if (g >= NG) return;
    float inv = 1.0f / fmaxf(cnt[g], 1.0f);
    float gx[H];
#pragma unroll
    for (int i = 0; i < H; i++) gx[i] = gsum[g * H + i] * inv;
    float o3 = b3[0];
#pragma unroll
    for (int j = 0; j < 16; j++) {
        float hh = sb2[j];
#pragma unroll
        for (int i = 0; i < H; i++) hh += gx[i] * sW2[i * 16 + j];
        hh = hh > 0.f ? hh : 0.f;
        o3 += hh * sW3[j];
    }
    out[g] = o3;
}

extern "C" void kernel_launch(void* const* d_in, const int* in_sizes, int n_in,
                              void* d_out, int out_size, void* d_ws, size_t ws_size,
                              hipStream_t stream) {
    const float* x      = (const float*)d_in[0];
    const float* eattr  = (const float*)d_in[1];
    const float* W_node = (const float*)d_in[2];
    const float* b_node = (const float*)d_in[3];
    const float* W_edge = (const float*)d_in[4];
    const float* b_edge = (const float*)d_in[5];
    const float* W_nn   = (const float*)d_in[6];
    const float* b_nn   = (const float*)d_in[7];
    const float* W_root = (const float*)d_in[8];
    const float* b_conv = (const float*)d_in[9];
    const float* gamma  = (const float*)d_in[10];
    const float* beta   = (const float*)d_in[11];
    const float* W2     = (const float*)d_in[12];
    const float* b2     = (const float*)d_in[13];
    const float* W3     = (const float*)d_in[14];
    const float* b3     = (const float*)d_in[15];
    const int* eidx     = (const int*)d_in[16];
    const int* batch    = (const int*)d_in[17];
    const int* src = eidx;
    const int* dst = eidx + NE;
    float* out = (float*)d_out;

    const size_t NNH = (size_t)NN * H;
    float* ws = (float*)d_ws;
    float* h      = ws;
    float* z      = h + NNH;
    float* u      = z + NNH;
    float* agg    = u + NNH;
    float* stats  = agg + NNH;                 // 64
    float* ea     = stats + 64;                // NE*32
    float* Wt     = ea + (size_t)NE * FE2;     // 3*32768
    int*   degB   = (int*)(Wt + (size_t)NL * 32768);   // NB
    float* gsum   = (float*)(degB + NB);       // NG*32 (contiguous with degB,cnt: one memset)
    float* cnt    = gsum + (size_t)NG * H;     // NG
    int*   rowptrB = (int*)(cnt + NG);         // NB+1
    int*   cursorB = rowptrB + NB + 1;         // NB
    int*   eid    = cursorB + NB;              // NE

    // zero degB | gsum | cnt in one shot
    hipMemsetAsync(degB, 0, (NB + NG * H + NG) * sizeof(int), stream);

    // mega prep: Wt repack (384) | edge emb (25000) | degB/cnt (782) | emb+lin0 (6250)
    k_prep<<<384 + 25000 + 782 + 6250, 256, 0, stream>>>(
        W_nn, Wt, eattr, W_edge, b_edge, ea, src, batch, degB, cnt,
        x, W_node, b_node, W_root, b_conv, b_nn, h, z, u, agg);
    k_scanB<<<1, 1024, 0, stream>>>(degB, rowptrB, cursorB);
    k_fill<<<(NE + 255) / 256, 256, 0, stream>>>(src, cursorB, eid);

    for (int l = 0; l < NL; l++) {
        k_conv<<<NB, 256, 0, stream>>>(h, u, ea, Wt + (size_t)l * 32768,
                                       rowptrB, eid, src, dst, agg, stats);
        k_add_stats<<<512, 256, 0, stream>>>(z, agg, stats);
        if (l < NL - 1) {
            k_bn_lin<<<NB, 256, 0, stream>>>(z, stats, gamma + l * H, beta + l * H,
                                             W_root + (l + 1) * H * H,
                                             b_conv + (l + 1) * H,
                                             b_nn + (size_t)(l + 1) * H * H,
                                             h, z, u);
        } else {
            k_bn_pool<<<NB, 256, 0, stream>>>(z, stats, gamma + l * H, beta + l * H,
                                              batch, gsum);
        }
    }

    k_head<<<2, 256, 0, stream>>>(gsum, cnt, W2, b2, W3, b3, out);
}